// Round 20
// baseline (55.873 us; speedup 1.0000x reference)
//
#include <hip/hip_runtime.h>
#include <math.h>

#define DF 512
#define NEMAX 89
#define TPAD 260   // ushorts per padded T row (130 words, 16 start banks)
#define T1PAD 17

typedef __attribute__((ext_vector_type(4))) unsigned short ushort4v;

__device__ __constant__ int c_lidx[16] = {0,1,1,1,2,2,2,2,2,3,3,3,3,3,3,3};

__device__ inline float bf2f(unsigned short s) {
    union { unsigned int u; float f; } x;
    x.u = ((unsigned int)s) << 16;
    return x.f;
}
__device__ inline unsigned short f2bf(float f) {
    union { float f; unsigned int u; } x; x.f = f;
    unsigned int r = x.u + 0x7fffu + ((x.u >> 16) & 1u);
    return (unsigned short)(r >> 16);
}

__device__ inline void sh_eval(float x, float y, float z, float* o)
{
    float x2 = x*x, y2 = y*y, z2 = z*z;
    o[0]  = 0.28209479177387814f;
    o[1]  = 0.4886025119029199f*y;
    o[2]  = 0.4886025119029199f*z;
    o[3]  = 0.4886025119029199f*x;
    o[4]  = 1.0925484305920792f*x*y;
    o[5]  = 1.0925484305920792f*y*z;
    o[6]  = 0.31539156525252005f*(3.0f*z2 - 1.0f);
    o[7]  = 1.0925484305920792f*x*z;
    o[8]  = 0.5462742152960396f*(x2 - y2);
    o[9]  = 0.5900435899266435f*y*(3.0f*x2 - y2);
    o[10] = 2.890611442640554f*x*y*z;
    o[11] = 0.4570457994644658f*y*(5.0f*z2 - 1.0f);
    o[12] = 0.3731763325901154f*z*(5.0f*z2 - 3.0f);
    o[13] = 0.4570457994644658f*x*(5.0f*z2 - 1.0f);
    o[14] = 1.445305721320277f*z*(x2 - y2);
    o[15] = 0.5900435899266435f*x*(x2 - 3.0f*y2);
}

__device__ inline void edge_dir(const float* __restrict__ pos, int s, int d,
                                float cx, float cy, float cz,
                                float& x, float& y, float& z)
{
    float ex = pos[d*3+0] - pos[s*3+0];
    float ey = pos[d*3+1] - pos[s*3+1];
    float ez = pos[d*3+2] - pos[s*3+2];
    ex -= rintf(ex/cx)*cx;
    ey -= rintf(ey/cy)*cy;
    ez -= rintf(ez/cz)*cz;
    float len = fmaxf(sqrtf(ex*ex + ey*ey + ez*ez), 1e-8f);
    x = ex/len; y = ey/len; z = ez/len;
}

// us[c*16+m] = sum_d tw1[l(m)][c][d] * v[d*16+m]   (256 threads, 2 outputs each)
__device__ inline void compute_u1(const float* __restrict__ tw1,
                                  const float* __restrict__ v,
                                  float* __restrict__ us, int t)
{
    #pragma unroll
    for (int rep = 0; rep < 2; rep++) {
        int f = t + rep*256;
        int c = f >> 4, m = f & 15, l = c_lidx[m];
        float u = 0.0f;
        #pragma unroll
        for (int d = 0; d < 32; d++) u = fmaf(tw1[l*1024 + c*32 + d], v[d*16 + m], u);
        us[f] = u;
    }
}

// K1: [0,64) vtmp=lw1@ow (wave-per-row); [64,128) wv0=lw0@ow; rest: zero yacc + out
__global__ __launch_bounds__(512) void k_setup(const float* __restrict__ lw1,
                                               const float* __restrict__ lw0,
                                               const float* __restrict__ ow,
                                               float* __restrict__ vtmp,
                                               float* __restrict__ wv0,
                                               uint4* __restrict__ yacc4, int nyacc4,
                                               float* __restrict__ out)
{
    int b = blockIdx.x, t = threadIdx.x;
    if (b < 128) {
        const float* w = (b < 64) ? lw1 : lw0;
        float* v = (b < 64) ? vtmp : wv0;
        int bb = b & 63;
        int r = bb*8 + (t >> 6);
        int lane = t & 63;
        const float* row = w + (size_t)r * DF;
        float s = 0.0f;
        #pragma unroll
        for (int j = 0; j < 8; j++) s += row[lane + j*64] * ow[lane + j*64];
        #pragma unroll
        for (int off = 32; off > 0; off >>= 1) s += __shfl_xor(s, off, 64);
        if (lane == 0) v[r] = s;
    } else {
        int i = (b - 128)*512 + t;
        if (i < nyacc4) yacc4[i] = make_uint4(0, 0, 0, 0);
        if (i == 0) out[0] = 0.0f;
    }
}

// K2: [0,NE) element blocks (u1 + local tf + T-direct + t1 + hf + embdot);
//     [NE] bias; (NE, NE+EB] SH+yacc atomic blocks (packed mapping).
__global__ __launch_bounds__(256) void k_mid(const float* __restrict__ pos,
                                             const int* __restrict__ src,
                                             const int* __restrict__ dst,
                                             const float* __restrict__ cell,
                                             const float* __restrict__ vtmp,
                                             const float* __restrict__ wv0,
                                             const float* __restrict__ tw1,
                                             const float* __restrict__ tw0,
                                             const float* __restrict__ lw0,
                                             const float* __restrict__ lb0,
                                             const float* __restrict__ lb1,
                                             const float* __restrict__ ow,
                                             const float* __restrict__ ob,
                                             const float* __restrict__ emb,
                                             float* __restrict__ yacc,
                                             unsigned short* __restrict__ Tbf,
                                             float* __restrict__ t1,
                                             float* __restrict__ hf,
                                             float* __restrict__ embdot,
                                             float* __restrict__ out,
                                             int E, int N, int NE)
{
    __shared__ __align__(16) float smem[256*17 + 256];   // 18.4 KB (atomic role max)
    int b = blockIdx.x, t = threadIdx.x;
    if (b < NE) {
        int a = b;
        float* us = smem;           // 512
        float* tf = smem + 512;     // 512 (later reused as r2)
        float* nf = smem + 1024;    // 512 (later reused as r1)
        nf[t] = emb[(size_t)a*DF + t]; nf[t+256] = emb[(size_t)a*DF + t + 256];
        compute_u1(tw1, vtmp, us, t);
        __syncthreads();
        #pragma unroll
        for (int rep = 0; rep < 2; rep++) {
            int f = t + rep*256;
            int dd = f >> 4, mm2 = f & 15;
            int l2 = c_lidx[mm2];
            float acc = 0.0f;
            #pragma unroll
            for (int c2 = 0; c2 < 32; c2++)
                acc = fmaf(nf[c2*16 + mm2], tw0[l2*1024 + c2*32 + dd], acc);
            tf[f] = acc;
        }
        __syncthreads();
        int mm = t >> 4, m = t & 15;
        float acc = 0.0f;
        #pragma unroll
        for (int d = 0; d < 32; d++) {
            const float* lrow = lw0 + (size_t)(d*16 + mm)*DF + m;
            float g = 0.0f;
            #pragma unroll
            for (int c = 0; c < 32; c++) g = fmaf(lrow[c*16], us[c*16 + m], g);
            acc = fmaf(tf[d*16 + mm], g, acc);
        }
        Tbf[(size_t)a*256 + mm*16 + m] = f2bf(acc);
        if (t < 16) {
            float s1 = 0.0f;
            #pragma unroll
            for (int d = 0; d < 32; d++) s1 = fmaf(tf[d*16 + t], wv0[d*16 + t], s1);
            t1[(size_t)a*16 + t] = s1;
        }
        __syncthreads();
        float e0 = nf[t], e1 = nf[t+256];
        tf[t]       = (e0 + lb0[t])     * us[t];
        tf[t + 256] = (e1 + lb0[t+256]) * us[t+256];
        nf[t] = e0*ow[t] + e1*ow[t+256];
        __syncthreads();
        for (int s = 128; s > 0; s >>= 1) {
            if (t < s) nf[t] += nf[t + s];
            __syncthreads();
        }
        if (t < 16) {
            float s = 0.0f;
            #pragma unroll
            for (int c = 0; c < 32; c++) s += tf[c*16 + t];
            hf[(size_t)a*16 + t] = s;
        }
        if (t == 0) embdot[a] = nf[0];
    } else if (b == NE) {
        float* red = smem;
        red[t] = (lb0[t] + lb1[t])*ow[t] + (lb0[t+256] + lb1[t+256])*ow[t+256];
        __syncthreads();
        for (int s = 128; s > 0; s >>= 1) {
            if (t < s) red[t] += red[t + s];
            __syncthreads();
        }
        if (t == 0) atomicAdd(out, (float)N * (red[0] + ob[0]));
    } else {
        // ---- SH + yacc atomics; PACKED mapping (16 lanes -> one row/cacheline) ----
        float* Yl = smem;                       // [256][17]
        int* sAl = (int*)(smem + 256*17);
        int be = b - NE - 1;
        int e = be*256 + t;
        float cx = cell[0], cy = cell[4], cz = cell[8];
        if (e < E) {
            int s = src[e], d = dst[e];
            float x, y, z;
            edge_dir(pos, s, d, cx, cy, cz, x, y, z);
            float o[16];
            sh_eval(x, y, z, o);
            #pragma unroll
            for (int j = 0; j < 16; j++) Yl[t*17 + j] = o[j];
            sAl[t] = s;
        }
        __syncthreads();
        int lastvalid = min(256, E - be*256);
        #pragma unroll
        for (int j = 0; j < 16; j++) {
            int idx = j*256 + t;
            int el = idx >> 4, m = idx & 15;
            if (el < lastvalid)
                atomicAdd(&yacc[(size_t)sAl[el]*16 + m], Yl[el*17 + m]);
        }
    }
}

// K3: edge-parallel energy; 512 threads/block -> 3 blocks/CU (159KB LDS), 24 waves/CU.
__global__ __launch_bounds__(512) void k_energy(const float* __restrict__ pos,
                                                const int* __restrict__ src,
                                                const int* __restrict__ dst,
                                                const int* __restrict__ an,
                                                const float* __restrict__ cell,
                                                const float* __restrict__ yacc,
                                                const unsigned short* __restrict__ Tbf,
                                                const float* __restrict__ t1,
                                                const float* __restrict__ hf,
                                                const float* __restrict__ embdot,
                                                float* __restrict__ out,
                                                int E, int N, int NE)
{
    __shared__ __align__(16) unsigned short Ts[NEMAX * TPAD];
    __shared__ float t1s[NEMAX * T1PAD];
    __shared__ float wred[8];
    int t = threadIdx.x;
    int nchunk = NE * 64;
    for (int c = t; c < nchunk; c += 512) {
        int a = c >> 6, k = c & 63;
        *(ushort4v*)&Ts[a*TPAD + k*4] = *(const ushort4v*)&Tbf[(size_t)a*256 + k*4];
    }
    for (int i = t; i < NE*16; i += 512) {
        int a = i >> 4, mm = i & 15;
        t1s[a*T1PAD + mm] = t1[i] + hf[i];   // hf folded (yacc expansion identity)
    }
    __syncthreads();

    int i = blockIdx.x * 512 + t;
    float s = 0.0f;
    if (i < E) {
        int sn = src[i], d = dst[i];
        int a = an[sn];
        float x, y, z;
        edge_dir(pos, sn, d, cell[0], cell[4], cell[8], x, y, z);
        float ov[16];
        sh_eval(x, y, z, ov);
        const float4* dp = (const float4*)(yacc + (size_t)d*16);
        float4 D0 = dp[0], D1 = dp[1], D2 = dp[2], D3 = dp[3];
        const unsigned short* Ta = &Ts[a * TPAD];
        const float* ta1 = &t1s[a * T1PAD];
        #pragma unroll
        for (int mm = 0; mm < 16; mm++) {
            ushort4v q0 = *(const ushort4v*)&Ta[mm*16];
            ushort4v q1 = *(const ushort4v*)&Ta[mm*16 + 4];
            ushort4v q2 = *(const ushort4v*)&Ta[mm*16 + 8];
            ushort4v q3 = *(const ushort4v*)&Ta[mm*16 + 12];
            float dotv = bf2f(q0[0])*D0.x + bf2f(q0[1])*D0.y + bf2f(q0[2])*D0.z + bf2f(q0[3])*D0.w
                       + bf2f(q1[0])*D1.x + bf2f(q1[1])*D1.y + bf2f(q1[2])*D1.z + bf2f(q1[3])*D1.w
                       + bf2f(q2[0])*D2.x + bf2f(q2[1])*D2.y + bf2f(q2[2])*D2.z + bf2f(q2[3])*D2.w
                       + bf2f(q3[0])*D3.x + bf2f(q3[1])*D3.y + bf2f(q3[2])*D3.z + bf2f(q3[3])*D3.w;
            s = fmaf(ov[mm], dotv + ta1[mm], s);
        }
    } else if (i < E + N) {
        s = embdot[an[i - E]];
    }
    #pragma unroll
    for (int off = 32; off > 0; off >>= 1) s += __shfl_xor(s, off, 64);
    int lane = t & 63, w = t >> 6;
    if (lane == 0) wred[w] = s;
    __syncthreads();
    if (t == 0) {
        float tot = 0.0f;
        #pragma unroll
        for (int j = 0; j < 8; j++) tot += wred[j];
        atomicAdd(out, tot);
    }
}

extern "C" void kernel_launch(void* const* d_in, const int* in_sizes, int n_in,
                              void* d_out, int out_size, void* d_ws, size_t ws_size,
                              hipStream_t stream)
{
    const float* pos  = (const float*)d_in[0];
    const float* cell = (const float*)d_in[1];
    const int*   an   = (const int*)d_in[2];
    const int*   ei   = (const int*)d_in[3];
    const float* emb  = (const float*)d_in[4];
    const float* tw0  = (const float*)d_in[5];
    const float* lw0  = (const float*)d_in[6];
    const float* lb0  = (const float*)d_in[7];
    const float* tw1  = (const float*)d_in[8];
    const float* lw1  = (const float*)d_in[9];
    const float* lb1  = (const float*)d_in[10];
    const float* ow   = (const float*)d_in[11];
    const float* ob   = (const float*)d_in[12];
    int N  = in_sizes[0] / 3;
    int E  = in_sizes[3] / 2;
    int NE = in_sizes[4] / DF;   // 89 elements
    const int* src = ei;
    const int* dst = ei + E;

    char* ws = (char*)d_ws;
    size_t off = 0;
    auto alloc = [&](size_t bytes) { void* p = ws + off; off += (bytes + 255) / 256 * 256; return p; };

    float* vtmp   = (float*)alloc(DF * 4);
    float* wv0    = (float*)alloc(DF * 4);
    unsigned short* Tbf = (unsigned short*)alloc((size_t)NE * 256 * 2);
    float* t1     = (float*)alloc((size_t)NE * 16 * 4);
    float* hf     = (float*)alloc((size_t)NE * 16 * 4);
    float* embdot = (float*)alloc((size_t)NE * 4);
    float* yacc   = (float*)alloc((size_t)N * 16 * 4);

    float* out = (float*)d_out;

    int nyacc4 = N * 4;
    int zblocks = (nyacc4 + 511) / 512;
    k_setup<<<128 + zblocks, 512, 0, stream>>>(
        lw1, lw0, ow, vtmp, wv0, (uint4*)yacc, nyacc4, out);

    int EB = (E + 255) / 256;
    k_mid<<<NE + 1 + EB, 256, 0, stream>>>(
        pos, src, dst, cell, vtmp, wv0, tw1, tw0, lw0, lb0, lb1, ow, ob, emb,
        yacc, Tbf, t1, hf, embdot, out, E, N, NE);

    k_energy<<<(E + N + 511) / 512, 512, 0, stream>>>(
        pos, src, dst, an, cell, yacc, Tbf, t1, hf, embdot, out, E, N, NE);
}

// Round 21
// 49.554 us; speedup vs baseline: 1.1275x; 1.1275x over previous
//
#include <hip/hip_runtime.h>
#include <math.h>

#define DF 512
#define NEMAX 89
#define TPAD 260   // ushorts per padded T row (130 words, 16 start banks)
#define T1PAD 17

typedef __attribute__((ext_vector_type(4))) unsigned short ushort4v;

__device__ __constant__ int c_lidx[16] = {0,1,1,1,2,2,2,2,2,3,3,3,3,3,3,3};

__device__ inline float bf2f(unsigned short s) {
    union { unsigned int u; float f; } x;
    x.u = ((unsigned int)s) << 16;
    return x.f;
}
__device__ inline unsigned short f2bf(float f) {
    union { float f; unsigned int u; } x; x.f = f;
    unsigned int r = x.u + 0x7fffu + ((x.u >> 16) & 1u);
    return (unsigned short)(r >> 16);
}

__device__ inline void sh_eval(float x, float y, float z, float* o)
{
    float x2 = x*x, y2 = y*y, z2 = z*z;
    o[0]  = 0.28209479177387814f;
    o[1]  = 0.4886025119029199f*y;
    o[2]  = 0.4886025119029199f*z;
    o[3]  = 0.4886025119029199f*x;
    o[4]  = 1.0925484305920792f*x*y;
    o[5]  = 1.0925484305920792f*y*z;
    o[6]  = 0.31539156525252005f*(3.0f*z2 - 1.0f);
    o[7]  = 1.0925484305920792f*x*z;
    o[8]  = 0.5462742152960396f*(x2 - y2);
    o[9]  = 0.5900435899266435f*y*(3.0f*x2 - y2);
    o[10] = 2.890611442640554f*x*y*z;
    o[11] = 0.4570457994644658f*y*(5.0f*z2 - 1.0f);
    o[12] = 0.3731763325901154f*z*(5.0f*z2 - 3.0f);
    o[13] = 0.4570457994644658f*x*(5.0f*z2 - 1.0f);
    o[14] = 1.445305721320277f*z*(x2 - y2);
    o[15] = 0.5900435899266435f*x*(x2 - 3.0f*y2);
}

__device__ inline void edge_dir(const float* __restrict__ pos, int s, int d,
                                float cx, float cy, float cz,
                                float& x, float& y, float& z)
{
    float ex = pos[d*3+0] - pos[s*3+0];
    float ey = pos[d*3+1] - pos[s*3+1];
    float ez = pos[d*3+2] - pos[s*3+2];
    ex -= rintf(ex/cx)*cx;
    ey -= rintf(ey/cy)*cy;
    ez -= rintf(ez/cz)*cz;
    float len = fmaxf(sqrtf(ex*ex + ey*ey + ez*ez), 1e-8f);
    x = ex/len; y = ey/len; z = ez/len;
}

// us[c*16+m] = sum_d tw1[l(m)][c][d] * v[d*16+m]   (256 threads, 2 outputs each)
__device__ inline void compute_u1(const float* __restrict__ tw1,
                                  const float* __restrict__ v,
                                  float* __restrict__ us, int t)
{
    #pragma unroll
    for (int rep = 0; rep < 2; rep++) {
        int f = t + rep*256;
        int c = f >> 4, m = f & 15, l = c_lidx[m];
        float u = 0.0f;
        #pragma unroll
        for (int d = 0; d < 32; d++) u = fmaf(tw1[l*1024 + c*32 + d], v[d*16 + m], u);
        us[f] = u;
    }
}

// K1: [0,64) vtmp=lw1@ow (wave-per-row); [64,128) wv0=lw0@ow; rest: zero yacc + out
__global__ __launch_bounds__(512) void k_setup(const float* __restrict__ lw1,
                                               const float* __restrict__ lw0,
                                               const float* __restrict__ ow,
                                               float* __restrict__ vtmp,
                                               float* __restrict__ wv0,
                                               uint4* __restrict__ yacc4, int nyacc4,
                                               float* __restrict__ out)
{
    int b = blockIdx.x, t = threadIdx.x;
    if (b < 128) {
        const float* w = (b < 64) ? lw1 : lw0;
        float* v = (b < 64) ? vtmp : wv0;
        int bb = b & 63;
        int r = bb*8 + (t >> 6);
        int lane = t & 63;
        const float* row = w + (size_t)r * DF;
        float s = 0.0f;
        #pragma unroll
        for (int j = 0; j < 8; j++) s += row[lane + j*64] * ow[lane + j*64];
        #pragma unroll
        for (int off = 32; off > 0; off >>= 1) s += __shfl_xor(s, off, 64);
        if (lane == 0) v[r] = s;
    } else {
        int i = (b - 128)*512 + t;
        if (i < nyacc4) yacc4[i] = make_uint4(0, 0, 0, 0);
        if (i == 0) out[0] = 0.0f;
    }
}

// K2: [0,NE) element blocks (u1 + local tf + T-direct + t1 + hf + embdot);
//     [NE] bias; (NE, NE+EB] SH+yacc atomic blocks (packed mapping).
__global__ __launch_bounds__(256) void k_mid(const float* __restrict__ pos,
                                             const int* __restrict__ src,
                                             const int* __restrict__ dst,
                                             const float* __restrict__ cell,
                                             const float* __restrict__ vtmp,
                                             const float* __restrict__ wv0,
                                             const float* __restrict__ tw1,
                                             const float* __restrict__ tw0,
                                             const float* __restrict__ lw0,
                                             const float* __restrict__ lb0,
                                             const float* __restrict__ lb1,
                                             const float* __restrict__ ow,
                                             const float* __restrict__ ob,
                                             const float* __restrict__ emb,
                                             float* __restrict__ yacc,
                                             unsigned short* __restrict__ Tbf,
                                             float* __restrict__ t1,
                                             float* __restrict__ hf,
                                             float* __restrict__ embdot,
                                             float* __restrict__ out,
                                             int E, int N, int NE)
{
    __shared__ __align__(16) float smem[256*17 + 256];   // 18.4 KB (atomic role max)
    int b = blockIdx.x, t = threadIdx.x;
    if (b < NE) {
        int a = b;
        float* us = smem;           // 512
        float* tf = smem + 512;     // 512 (later reused as r2)
        float* nf = smem + 1024;    // 512 (later reused as r1)
        nf[t] = emb[(size_t)a*DF + t]; nf[t+256] = emb[(size_t)a*DF + t + 256];
        compute_u1(tw1, vtmp, us, t);
        __syncthreads();
        #pragma unroll
        for (int rep = 0; rep < 2; rep++) {
            int f = t + rep*256;
            int dd = f >> 4, mm2 = f & 15;
            int l2 = c_lidx[mm2];
            float acc = 0.0f;
            #pragma unroll
            for (int c2 = 0; c2 < 32; c2++)
                acc = fmaf(nf[c2*16 + mm2], tw0[l2*1024 + c2*32 + dd], acc);
            tf[f] = acc;
        }
        __syncthreads();
        int mm = t >> 4, m = t & 15;
        float acc = 0.0f;
        #pragma unroll
        for (int d = 0; d < 32; d++) {
            const float* lrow = lw0 + (size_t)(d*16 + mm)*DF + m;
            float g = 0.0f;
            #pragma unroll
            for (int c = 0; c < 32; c++) g = fmaf(lrow[c*16], us[c*16 + m], g);
            acc = fmaf(tf[d*16 + mm], g, acc);
        }
        Tbf[(size_t)a*256 + mm*16 + m] = f2bf(acc);
        if (t < 16) {
            float s1 = 0.0f;
            #pragma unroll
            for (int d = 0; d < 32; d++) s1 = fmaf(tf[d*16 + t], wv0[d*16 + t], s1);
            t1[(size_t)a*16 + t] = s1;
        }
        __syncthreads();
        float e0 = nf[t], e1 = nf[t+256];
        tf[t]       = (e0 + lb0[t])     * us[t];
        tf[t + 256] = (e1 + lb0[t+256]) * us[t+256];
        nf[t] = e0*ow[t] + e1*ow[t+256];
        __syncthreads();
        for (int s = 128; s > 0; s >>= 1) {
            if (t < s) nf[t] += nf[t + s];
            __syncthreads();
        }
        if (t < 16) {
            float s = 0.0f;
            #pragma unroll
            for (int c = 0; c < 32; c++) s += tf[c*16 + t];
            hf[(size_t)a*16 + t] = s;
        }
        if (t == 0) embdot[a] = nf[0];
    } else if (b == NE) {
        float* red = smem;
        red[t] = (lb0[t] + lb1[t])*ow[t] + (lb0[t+256] + lb1[t+256])*ow[t+256];
        __syncthreads();
        for (int s = 128; s > 0; s >>= 1) {
            if (t < s) red[t] += red[t + s];
            __syncthreads();
        }
        if (t == 0) atomicAdd(out, (float)N * (red[0] + ob[0]));
    } else {
        // ---- SH + yacc atomics; PACKED mapping (16 lanes -> one row/cacheline) ----
        float* Yl = smem;                       // [256][17]
        int* sAl = (int*)(smem + 256*17);
        int be = b - NE - 1;
        int e = be*256 + t;
        float cx = cell[0], cy = cell[4], cz = cell[8];
        if (e < E) {
            int s = src[e], d = dst[e];
            float x, y, z;
            edge_dir(pos, s, d, cx, cy, cz, x, y, z);
            float o[16];
            sh_eval(x, y, z, o);
            #pragma unroll
            for (int j = 0; j < 16; j++) Yl[t*17 + j] = o[j];
            sAl[t] = s;
        }
        __syncthreads();
        int lastvalid = min(256, E - be*256);
        #pragma unroll
        for (int j = 0; j < 16; j++) {
            int idx = j*256 + t;
            int el = idx >> 4, m = idx & 15;
            if (el < lastvalid)
                atomicAdd(&yacc[(size_t)sAl[el]*16 + m], Yl[el*17 + m]);
        }
    }
}

// K3: edge-parallel energy; 1024 threads; Ts bf16 TPAD=260; t1s = t1 + hf (folded);
// node tail = embdot only.
__global__ __launch_bounds__(1024) void k_energy(const float* __restrict__ pos,
                                                 const int* __restrict__ src,
                                                 const int* __restrict__ dst,
                                                 const int* __restrict__ an,
                                                 const float* __restrict__ cell,
                                                 const float* __restrict__ yacc,
                                                 const unsigned short* __restrict__ Tbf,
                                                 const float* __restrict__ t1,
                                                 const float* __restrict__ hf,
                                                 const float* __restrict__ embdot,
                                                 float* __restrict__ out,
                                                 int E, int N, int NE)
{
    __shared__ __align__(16) unsigned short Ts[NEMAX * TPAD];
    __shared__ float t1s[NEMAX * T1PAD];
    __shared__ float wred[16];
    int t = threadIdx.x;
    int nchunk = NE * 64;
    for (int c = t; c < nchunk; c += 1024) {
        int a = c >> 6, k = c & 63;
        *(ushort4v*)&Ts[a*TPAD + k*4] = *(const ushort4v*)&Tbf[(size_t)a*256 + k*4];
    }
    for (int i = t; i < NE*16; i += 1024) {
        int a = i >> 4, mm = i & 15;
        t1s[a*T1PAD + mm] = t1[i] + hf[i];   // hf folded (yacc expansion identity)
    }
    __syncthreads();

    int i = blockIdx.x * 1024 + t;
    float s = 0.0f;
    if (i < E) {
        int sn = src[i], d = dst[i];
        int a = an[sn];
        float x, y, z;
        edge_dir(pos, sn, d, cell[0], cell[4], cell[8], x, y, z);
        float ov[16];
        sh_eval(x, y, z, ov);
        const float4* dp = (const float4*)(yacc + (size_t)d*16);
        float4 D0 = dp[0], D1 = dp[1], D2 = dp[2], D3 = dp[3];
        const unsigned short* Ta = &Ts[a * TPAD];
        const float* ta1 = &t1s[a * T1PAD];
        #pragma unroll
        for (int mm = 0; mm < 16; mm++) {
            ushort4v q0 = *(const ushort4v*)&Ta[mm*16];
            ushort4v q1 = *(const ushort4v*)&Ta[mm*16 + 4];
            ushort4v q2 = *(const ushort4v*)&Ta[mm*16 + 8];
            ushort4v q3 = *(const ushort4v*)&Ta[mm*16 + 12];
            float dotv = bf2f(q0[0])*D0.x + bf2f(q0[1])*D0.y + bf2f(q0[2])*D0.z + bf2f(q0[3])*D0.w
                       + bf2f(q1[0])*D1.x + bf2f(q1[1])*D1.y + bf2f(q1[2])*D1.z + bf2f(q1[3])*D1.w
                       + bf2f(q2[0])*D2.x + bf2f(q2[1])*D2.y + bf2f(q2[2])*D2.z + bf2f(q2[3])*D2.w
                       + bf2f(q3[0])*D3.x + bf2f(q3[1])*D3.y + bf2f(q3[2])*D3.z + bf2f(q3[3])*D3.w;
            s = fmaf(ov[mm], dotv + ta1[mm], s);
        }
    } else if (i < E + N) {
        s = embdot[an[i - E]];
    }
    #pragma unroll
    for (int off = 32; off > 0; off >>= 1) s += __shfl_xor(s, off, 64);
    int lane = t & 63, w = t >> 6;
    if (lane == 0) wred[w] = s;
    __syncthreads();
    if (t == 0) {
        float tot = 0.0f;
        #pragma unroll
        for (int j = 0; j < 16; j++) tot += wred[j];
        atomicAdd(out, tot);
    }
}

extern "C" void kernel_launch(void* const* d_in, const int* in_sizes, int n_in,
                              void* d_out, int out_size, void* d_ws, size_t ws_size,
                              hipStream_t stream)
{
    const float* pos  = (const float*)d_in[0];
    const float* cell = (const float*)d_in[1];
    const int*   an   = (const int*)d_in[2];
    const int*   ei   = (const int*)d_in[3];
    const float* emb  = (const float*)d_in[4];
    const float* tw0  = (const float*)d_in[5];
    const float* lw0  = (const float*)d_in[6];
    const float* lb0  = (const float*)d_in[7];
    const float* tw1  = (const float*)d_in[8];
    const float* lw1  = (const float*)d_in[9];
    const float* lb1  = (const float*)d_in[10];
    const float* ow   = (const float*)d_in[11];
    const float* ob   = (const float*)d_in[12];
    int N  = in_sizes[0] / 3;
    int E  = in_sizes[3] / 2;
    int NE = in_sizes[4] / DF;   // 89 elements
    const int* src = ei;
    const int* dst = ei + E;

    char* ws = (char*)d_ws;
    size_t off = 0;
    auto alloc = [&](size_t bytes) { void* p = ws + off; off += (bytes + 255) / 256 * 256; return p; };

    float* vtmp   = (float*)alloc(DF * 4);
    float* wv0    = (float*)alloc(DF * 4);
    unsigned short* Tbf = (unsigned short*)alloc((size_t)NE * 256 * 2);
    float* t1     = (float*)alloc((size_t)NE * 16 * 4);
    float* hf     = (float*)alloc((size_t)NE * 16 * 4);
    float* embdot = (float*)alloc((size_t)NE * 4);
    float* yacc   = (float*)alloc((size_t)N * 16 * 4);

    float* out = (float*)d_out;

    int nyacc4 = N * 4;
    int zblocks = (nyacc4 + 511) / 512;
    k_setup<<<128 + zblocks, 512, 0, stream>>>(
        lw1, lw0, ow, vtmp, wv0, (uint4*)yacc, nyacc4, out);

    int EB = (E + 255) / 256;
    k_mid<<<NE + 1 + EB, 256, 0, stream>>>(
        pos, src, dst, cell, vtmp, wv0, tw1, tw0, lw0, lb0, lb1, ow, ob, emb,
        yacc, Tbf, t1, hf, embdot, out, E, N, NE);

    k_energy<<<(E + N + 1023) / 1024, 1024, 0, stream>>>(
        pos, src, dst, an, cell, yacc, Tbf, t1, hf, embdot, out, E, N, NE);
}